// Round 1
// baseline (13662.022 us; speedup 1.0000x reference)
//
#include <hip/hip_runtime.h>
#include <hip/hip_cooperative_groups.h>

namespace cg = cooperative_groups;

#define V_ 32000
#define E_ 256
#define U_ 512
#define B_ 64
#define T_ 256
#define G_ 2048      // 4*U
#define KTOT 768     // E + U
#define WSTRIDE 772  // 768 + 4 pad (bank-conflict break, keeps 16B alignment)

// grid: 256 blocks x 512 threads, persistent cooperative kernel.
// block -> (dir, b-half of 32, u-slice of 8) ; weights for its 32 gate-cols live in LDS.
__global__ __launch_bounds__(512, 1)
void bilstm_kernel(const int* __restrict__ x,
                   const float* __restrict__ emb,
                   const float* __restrict__ Wf, const float* __restrict__ Rf,
                   const float* __restrict__ bf,
                   const float* __restrict__ Wb, const float* __restrict__ Rb,
                   const float* __restrict__ bb,
                   float* __restrict__ out, float* __restrict__ hbuf)
{
    __shared__ float Wl[32 * WSTRIDE];   // 98816 B, transposed weights [gc][k]
    __shared__ float zx[32 * 32];        // z exchange [gc][b_loc]
    __shared__ float cst[256];           // c state   [b_loc*8 + uu]

    const int blk = blockIdx.x;
    const int dir = blk >> 7;            // 0 fwd, 1 bwd
    const int rem = blk & 127;
    const int u0 = (rem >> 1) * 8;       // u-slice base
    const int b0base = (rem & 1) * 32;   // batch half

    const int tid = threadIdx.x;
    const int gc  = tid & 31;            // gate-col within block (0..31)
    const int bp  = tid >> 5;            // batch pair (0..15)
    const int gate = gc >> 3;
    const int uu   = gc & 7;
    const int g    = gate * 512 + u0 + uu;   // global gate column

    const float* Wd = dir ? Wb : Wf;
    const float* Rd = dir ? Rb : Rf;
    const float* bd = dir ? bb : bf;

    // ---- one-time: stage this block's 32 weight columns into LDS, transposed ----
    for (int k = bp; k < KTOT; k += 16) {
        float v = (k < E_) ? Wd[(size_t)k * G_ + g]
                           : Rd[(size_t)(k - E_) * G_ + g];
        Wl[gc * WSTRIDE + k] = v;
    }
    if (tid < 256) cst[tid] = 0.0f;

    // zero h double-buffer slot 0 (2 dirs x 64 x 512 = 65536 floats)
    {
        int idx = blk * 512 + tid;
        if (idx < 2 * B_ * U_) hbuf[idx] = 0.0f;
    }

    const float bias_g = bd[g];
    const int bg0 = b0base + bp * 2;
    const int bg1 = bg0 + 1;

    cg::grid_group grid = cg::this_grid();
    grid.sync();

    const float4* WlA = reinterpret_cast<const float4*>(&Wl[gc * WSTRIDE]);

    for (int s = 0; s < T_; ++s) {
        const int te  = dir ? (T_ - 1 - s) : s;
        const int cur = s & 1;
        const int nxt = cur ^ 1;

        float acc0 = bias_g, acc1 = bias_g;

        // ---- x-projection part: emb[x[b,te]] @ W  (K = 0..255) ----
        const float4* e0 = reinterpret_cast<const float4*>(
            emb + (size_t)x[bg0 * T_ + te] * E_);
        const float4* e1 = reinterpret_cast<const float4*>(
            emb + (size_t)x[bg1 * T_ + te] * E_);
        #pragma unroll 8
        for (int k4 = 0; k4 < E_ / 4; ++k4) {
            float4 w = WlA[k4];
            float4 a = e0[k4];
            float4 c = e1[k4];
            acc0 = fmaf(w.x, a.x, acc0); acc0 = fmaf(w.y, a.y, acc0);
            acc0 = fmaf(w.z, a.z, acc0); acc0 = fmaf(w.w, a.w, acc0);
            acc1 = fmaf(w.x, c.x, acc1); acc1 = fmaf(w.y, c.y, acc1);
            acc1 = fmaf(w.z, c.z, acc1); acc1 = fmaf(w.w, c.w, acc1);
        }

        // ---- recurrent part: h @ R  (K = 256..767) ----
        const float4* h0 = reinterpret_cast<const float4*>(
            hbuf + ((size_t)(cur * 2 + dir) * B_ + bg0) * U_);
        const float4* h1 = reinterpret_cast<const float4*>(
            hbuf + ((size_t)(cur * 2 + dir) * B_ + bg1) * U_);
        #pragma unroll 8
        for (int k4 = 0; k4 < U_ / 4; ++k4) {
            float4 w = WlA[E_ / 4 + k4];
            float4 a = h0[k4];
            float4 c = h1[k4];
            acc0 = fmaf(w.x, a.x, acc0); acc0 = fmaf(w.y, a.y, acc0);
            acc0 = fmaf(w.z, a.z, acc0); acc0 = fmaf(w.w, a.w, acc0);
            acc1 = fmaf(w.x, c.x, acc1); acc1 = fmaf(w.y, c.y, acc1);
            acc1 = fmaf(w.z, c.z, acc1); acc1 = fmaf(w.w, c.w, acc1);
        }

        zx[gc * 32 + (bp * 2 + 0)] = acc0;
        zx[gc * 32 + (bp * 2 + 1)] = acc1;
        __syncthreads();

        // ---- gate + state update: one (b,u) per thread (first 256 threads) ----
        if (tid < 256) {
            const int bl = tid >> 3;
            const int vv = tid & 7;
            const int b  = b0base + bl;
            const int u  = u0 + vv;

            float zi = zx[(0 * 8 + vv) * 32 + bl];
            float zf = zx[(1 * 8 + vv) * 32 + bl];
            float zg = zx[(2 * 8 + vv) * 32 + bl];
            float zo = zx[(3 * 8 + vv) * 32 + bl];

            float c_old = cst[tid];
            float fi = tanhf(zi);
            float ff = tanhf(zf);
            float fg = tanhf(zg);
            float fo = tanhf(zo);
            float cn = fmaf(ff, c_old, fi * fg);
            float hn = fo * tanhf(cn);

            bool m = (x[b * T_ + te] != 0);
            float h_old = hbuf[((size_t)(cur * 2 + dir) * B_ + b) * U_ + u];
            float hsel = m ? hn : h_old;
            float csel = m ? cn : c_old;

            cst[tid] = csel;
            hbuf[((size_t)(nxt * 2 + dir) * B_ + b) * U_ + u] = hsel;
            out[((size_t)b * T_ + te) * 1024 + dir * 512 + u] = hsel;
            if (dir == 1 && s == T_ - 1) {
                out[(size_t)B_ * T_ * 1024 + (size_t)b * U_ + u] = hsel;
            }
        }
        grid.sync();
    }
}

extern "C" void kernel_launch(void* const* d_in, const int* in_sizes, int n_in,
                              void* d_out, int out_size, void* d_ws, size_t ws_size,
                              hipStream_t stream) {
    const int*   x   = (const int*)d_in[0];
    const float* emb = (const float*)d_in[1];
    const float* Wf  = (const float*)d_in[2];
    const float* Rf  = (const float*)d_in[3];
    const float* bfp = (const float*)d_in[4];
    const float* Wb  = (const float*)d_in[5];
    const float* Rb  = (const float*)d_in[6];
    const float* bbp = (const float*)d_in[7];
    float* out  = (float*)d_out;
    float* hbuf = (float*)d_ws;   // 2 bufs x 2 dirs x 64 x 512 floats = 512 KB

    void* args[] = {
        (void*)&x, (void*)&emb,
        (void*)&Wf, (void*)&Rf, (void*)&bfp,
        (void*)&Wb, (void*)&Rb, (void*)&bbp,
        (void*)&out, (void*)&hbuf
    };
    hipLaunchCooperativeKernel((const void*)bilstm_kernel,
                               dim3(256), dim3(512), args, 0, stream);
}

// Round 2
// 13398.033 us; speedup vs baseline: 1.0197x; 1.0197x over previous
//
#include <hip/hip_runtime.h>
#include <hip/hip_cooperative_groups.h>

namespace cg = cooperative_groups;

#define V_ 32000
#define E_ 256
#define U_ 512
#define B_ 64
#define T_ 256
#define G_ 2048      // 4*U
#define KTOT 768     // E + U
#define WSTRIDE 772  // 768 + 4 pad (bank-conflict break, keeps 16B alignment)

// grid: 256 blocks x 512 threads, persistent cooperative kernel.
// block -> (dir, b-half of 32, u-slice of 8) ; weights for its 32 gate-cols live in LDS.
__global__ __launch_bounds__(512, 1)
void bilstm_kernel(const int* __restrict__ x,
                   const float* __restrict__ emb,
                   const float* __restrict__ Wf, const float* __restrict__ Rf,
                   const float* __restrict__ bf,
                   const float* __restrict__ Wb, const float* __restrict__ Rb,
                   const float* __restrict__ bb,
                   float* __restrict__ out, float* __restrict__ hbuf)
{
    __shared__ float Wl[32 * WSTRIDE];   // 98816 B, transposed weights [gc][k]
    __shared__ float zx[32 * 32];        // z exchange [gc][b_loc]
    __shared__ float cst[256];           // c state   [b_loc*8 + uu]

    const int blk = blockIdx.x;
    const int dir = blk >> 7;            // 0 fwd, 1 bwd
    const int rem = blk & 127;
    const int u0 = (rem >> 1) * 8;       // u-slice base
    const int b0base = (rem & 1) * 32;   // batch half

    const int tid = threadIdx.x;
    const int gc  = tid & 31;            // gate-col within block (0..31)
    const int bp  = tid >> 5;            // batch pair (0..15)
    const int gate = gc >> 3;
    const int uu   = gc & 7;
    const int g    = gate * 512 + u0 + uu;   // global gate column

    const float* Wd = dir ? Wb : Wf;
    const float* Rd = dir ? Rb : Rf;
    const float* bd = dir ? bb : bf;

    // ---- one-time: stage this block's 32 weight columns into LDS, transposed ----
    for (int k = bp; k < KTOT; k += 16) {
        float v = (k < E_) ? Wd[(size_t)k * G_ + g]
                           : Rd[(size_t)(k - E_) * G_ + g];
        Wl[gc * WSTRIDE + k] = v;
    }
    if (tid < 256) cst[tid] = 0.0f;

    // zero h double-buffer slot 0 (2 dirs x 64 x 512 = 65536 floats)
    {
        int idx = blk * 512 + tid;
        if (idx < 2 * B_ * U_) hbuf[idx] = 0.0f;
    }

    const float bias_g = bd[g];
    const int bg0 = b0base + bp * 2;
    const int bg1 = bg0 + 1;

    cg::grid_group grid = cg::this_grid();
    grid.sync();

    const float4* WlA = reinterpret_cast<const float4*>(&Wl[gc * WSTRIDE]);

    for (int s = 0; s < T_; ++s) {
        const int te  = dir ? (T_ - 1 - s) : s;
        const int cur = s & 1;
        const int nxt = cur ^ 1;

        float acc0 = bias_g, acc1 = bias_g;

        // ---- x-projection part: emb[x[b,te]] @ W  (K = 0..255) ----
        const float4* e0 = reinterpret_cast<const float4*>(
            emb + (size_t)x[bg0 * T_ + te] * E_);
        const float4* e1 = reinterpret_cast<const float4*>(
            emb + (size_t)x[bg1 * T_ + te] * E_);
        #pragma unroll 8
        for (int k4 = 0; k4 < E_ / 4; ++k4) {
            float4 w = WlA[k4];
            float4 a = e0[k4];
            float4 c = e1[k4];
            acc0 = fmaf(w.x, a.x, acc0); acc0 = fmaf(w.y, a.y, acc0);
            acc0 = fmaf(w.z, a.z, acc0); acc0 = fmaf(w.w, a.w, acc0);
            acc1 = fmaf(w.x, c.x, acc1); acc1 = fmaf(w.y, c.y, acc1);
            acc1 = fmaf(w.z, c.z, acc1); acc1 = fmaf(w.w, c.w, acc1);
        }

        // ---- recurrent part: h @ R  (K = 256..767) ----
        const float4* h0 = reinterpret_cast<const float4*>(
            hbuf + ((size_t)(cur * 2 + dir) * B_ + bg0) * U_);
        const float4* h1 = reinterpret_cast<const float4*>(
            hbuf + ((size_t)(cur * 2 + dir) * B_ + bg1) * U_);
        #pragma unroll 8
        for (int k4 = 0; k4 < U_ / 4; ++k4) {
            float4 w = WlA[E_ / 4 + k4];
            float4 a = h0[k4];
            float4 c = h1[k4];
            acc0 = fmaf(w.x, a.x, acc0); acc0 = fmaf(w.y, a.y, acc0);
            acc0 = fmaf(w.z, a.z, acc0); acc0 = fmaf(w.w, a.w, acc0);
            acc1 = fmaf(w.x, c.x, acc1); acc1 = fmaf(w.y, c.y, acc1);
            acc1 = fmaf(w.z, c.z, acc1); acc1 = fmaf(w.w, c.w, acc1);
        }

        zx[gc * 32 + (bp * 2 + 0)] = acc0;
        zx[gc * 32 + (bp * 2 + 1)] = acc1;
        __syncthreads();

        // ---- gate + state update: one (b,u) per thread (first 256 threads) ----
        if (tid < 256) {
            const int bl = tid >> 3;
            const int vv = tid & 7;
            const int b  = b0base + bl;
            const int u  = u0 + vv;

            float zi = zx[(0 * 8 + vv) * 32 + bl];
            float zf = zx[(1 * 8 + vv) * 32 + bl];
            float zg = zx[(2 * 8 + vv) * 32 + bl];
            float zo = zx[(3 * 8 + vv) * 32 + bl];

            float c_old = cst[tid];
            float fi = tanhf(zi);
            float ff = tanhf(zf);
            float fg = tanhf(zg);
            float fo = tanhf(zo);
            float cn = fmaf(ff, c_old, fi * fg);
            float hn = fo * tanhf(cn);

            bool m = (x[b * T_ + te] != 0);
            float h_old = hbuf[((size_t)(cur * 2 + dir) * B_ + b) * U_ + u];
            float hsel = m ? hn : h_old;
            float csel = m ? cn : c_old;

            cst[tid] = csel;
            hbuf[((size_t)(nxt * 2 + dir) * B_ + b) * U_ + u] = hsel;
            out[((size_t)b * T_ + te) * 1024 + dir * 512 + u] = hsel;
            if (dir == 1 && s == T_ - 1) {
                out[(size_t)B_ * T_ * 1024 + (size_t)b * U_ + u] = hsel;
            }
        }
        grid.sync();
    }
}

extern "C" void kernel_launch(void* const* d_in, const int* in_sizes, int n_in,
                              void* d_out, int out_size, void* d_ws, size_t ws_size,
                              hipStream_t stream) {
    const int*   x   = (const int*)d_in[0];
    const float* emb = (const float*)d_in[1];
    const float* Wf  = (const float*)d_in[2];
    const float* Rf  = (const float*)d_in[3];
    const float* bfp = (const float*)d_in[4];
    const float* Wb  = (const float*)d_in[5];
    const float* Rb  = (const float*)d_in[6];
    const float* bbp = (const float*)d_in[7];
    float* out  = (float*)d_out;
    float* hbuf = (float*)d_ws;   // 2 bufs x 2 dirs x 64 x 512 floats = 512 KB

    void* args[] = {
        (void*)&x, (void*)&emb,
        (void*)&Wf, (void*)&Rf, (void*)&bfp,
        (void*)&Wb, (void*)&Rb, (void*)&bbp,
        (void*)&out, (void*)&hbuf
    };
    hipLaunchCooperativeKernel((const void*)bilstm_kernel,
                               dim3(256), dim3(512), args, 0, stream);
}